// Round 10
// baseline (124.424 us; speedup 1.0000x reference)
//
#include <hip/hip_runtime.h>
#include <hip/hip_bf16.h>
#include <hip/hip_fp16.h>

// SkeletonLoss: out = sum_b mean_e ( ||p[b,s0]-p[b,s1]|| - init_len[e] )^2
// B=64, N=100000, E=200000.
//
// R9b (R9 with compile fix): barrier-free L2-resident transposed-f16 gather.
//  - transpose: register-only (no LDS/syncthreads). Thread = one point row n:
//    8 coalesced nontemporal 8-B loads (as u64 -- __builtin_nontemporal_load
//    rejects HIP_vector_type float2*; nt so single-use fp32 points don't
//    evict the f16 slice from L2), f16 convert in regs, 2 contiguous uint4
//    stores (regular, cached -> slice stays in the XCD L2).
//  - gather: 4 edges per lane-pair per iteration -> 8 independent 16 B row
//    loads in flight (MSHR fill), nontemporal edge stream.
// Layout: tp[slot][n] = 32 B row of both f16 coords of point n for the 8
// batches owned by XCD slot (slot = blockIdx.x & 7, round-robin heuristic);
// slice = N*32 B = 3.2 MB < 4 MB per-XCD L2 -> gathers are L2 hits in any
// order; one line request serves 8 batch-evals. No bucketing, no barriers,
// uniform static edge split. f16 rounding: zero-mean ~1e-3/edge, averaged
// over 200K edges -> ~1e-3 total vs threshold 3.28 (R8 measured absmax 0.0).

__global__ __launch_bounds__(1024) void transpose_kernel(
    const float2* __restrict__ pts, uint4* __restrict__ tp, int N)
{
    const int s = blockIdx.x & 7;
    const int n = (blockIdx.x >> 3) * 1024 + threadIdx.x;
    if (n >= N) return;
    const unsigned long long* pb =
        (const unsigned long long*)(pts + (size_t)s * 8 * N + n);
    union { __half2 h[8]; uint4 u[2]; } P;
    #pragma unroll
    for (int b = 0; b < 8; ++b) {
        union { unsigned long long q; float f[2]; } v;
        v.q = __builtin_nontemporal_load(pb + (size_t)b * N);
        P.h[b] = __floats2half2_rn(v.f[0], v.f[1]);
    }
    uint4* row = tp + ((size_t)s * N + n) * 2;
    row[0] = P.u[0];
    row[1] = P.u[1];
}

__device__ __forceinline__ float eval4(uint4 A, uint4 Bv, float l) {
    union { uint4 u; __half2 h[4]; } ua, ub;
    ua.u = A; ub.u = Bv;
    float acc = 0.0f;
    #pragma unroll
    for (int k = 0; k < 4; ++k) {
        float2 p = __half22float2(ua.h[k]);
        float2 q = __half22float2(ub.h[k]);
        float dx = p.x - q.x, dy = p.y - q.y;
        float d = sqrtf(fmaf(dx, dx, dy * dy)) - l;
        acc = fmaf(d, d, acc);
    }
    return acc;
}

__global__ __launch_bounds__(512) void gather_kernel(
    const uint4* __restrict__ tp, const long long* __restrict__ skel,
    const float* __restrict__ lenv, float* __restrict__ out,
    int N, int E, float inv_E)
{
    const int slot = blockIdx.x & 7;        // XCD affinity
    const int wid  = blockIdx.x >> 3;       // 0..63 within slot
    const int chunk = (E + 63) >> 6;
    const int start = wid * chunk;
    const int end   = min(E, start + chunk);
    const uint4* tg = tp + (size_t)slot * N * 2;

    const int tid = threadIdx.x;
    const int rl = tid >> 1, j = tid & 1;   // 2 lanes per edge; j = 16B half
    float acc = 0.0f;

    for (int base = start; base < end; base += 1024) {
        int e0 = base + rl, e1 = e0 + 256, e2 = e0 + 512, e3 = e0 + 768;
        bool v0 = e0 < end, v1 = e1 < end, v2 = e2 < end, v3 = e3 < end;
        // nontemporal edge stream (don't evict the resident tp slice)
        long long s0 = v0 ? __builtin_nontemporal_load(skel + e0) : 0;
        long long s1 = v1 ? __builtin_nontemporal_load(skel + e1) : 0;
        long long s2 = v2 ? __builtin_nontemporal_load(skel + e2) : 0;
        long long s3 = v3 ? __builtin_nontemporal_load(skel + e3) : 0;
        float l0 = v0 ? __builtin_nontemporal_load(lenv + e0) : 0.0f;
        float l1 = v1 ? __builtin_nontemporal_load(lenv + e1) : 0.0f;
        float l2 = v2 ? __builtin_nontemporal_load(lenv + e2) : 0.0f;
        float l3 = v3 ? __builtin_nontemporal_load(lenv + e3) : 0.0f;
        // 8 independent 16 B row loads in flight (lane pairs share a 32 B row)
        uint4 a0 = tg[(size_t)(unsigned)(int)(s0 & 0xffffffff) * 2 + j];
        uint4 b0 = tg[(size_t)(unsigned)(int)(s0 >> 32) * 2 + j];
        uint4 a1 = tg[(size_t)(unsigned)(int)(s1 & 0xffffffff) * 2 + j];
        uint4 b1 = tg[(size_t)(unsigned)(int)(s1 >> 32) * 2 + j];
        uint4 a2 = tg[(size_t)(unsigned)(int)(s2 & 0xffffffff) * 2 + j];
        uint4 b2 = tg[(size_t)(unsigned)(int)(s2 >> 32) * 2 + j];
        uint4 a3 = tg[(size_t)(unsigned)(int)(s3 & 0xffffffff) * 2 + j];
        uint4 b3 = tg[(size_t)(unsigned)(int)(s3 >> 32) * 2 + j];
        if (v0) acc += eval4(a0, b0, l0);
        if (v1) acc += eval4(a1, b1, l1);
        if (v2) acc += eval4(a2, b2, l2);
        if (v3) acc += eval4(a3, b3, l3);
    }

    // reduction: wave(64) shuffle -> LDS -> one atomic per block
    #pragma unroll
    for (int offx = 32; offx > 0; offx >>= 1)
        acc += __shfl_down(acc, offx, 64);
    __shared__ float wsum[8];
    const int lane = tid & 63, wave = tid >> 6;
    if (lane == 0) wsum[wave] = acc;
    __syncthreads();
    if (wave == 0) {
        float v = (lane < 8) ? wsum[lane] : 0.0f;
        #pragma unroll
        for (int offx = 4; offx > 0; offx >>= 1)
            v += __shfl_down(v, offx, 64);
        if (lane == 0) atomicAdd(out, v * inv_E);
    }
}

// ---------- fallback (R2 style, proven correct) ----------
__global__ __launch_bounds__(256) void skeleton_loss_fallback(
    const float2* __restrict__ pts, const int* __restrict__ skel,
    const float* __restrict__ init_len, float* __restrict__ out,
    int N, int E, float inv_E)
{
    const int L = blockIdx.x;
    const int slot = L & 7;
    const int j = L >> 3;
    int e = j * 256 + threadIdx.x;
    float acc = 0.0f;
    if (e < E) {
        int i0 = skel[2 * e], i1 = skel[2 * e + 1];
        float l0 = init_len[e];
        for (int bb = 0; bb < 8; ++bb) {
            const float2* p = pts + (size_t)(slot * 8 + bb) * N;
            float2 s = p[i0], d = p[i1];
            float dx = s.x - d.x, dy = s.y - d.y;
            float df = sqrtf(dx * dx + dy * dy) - l0;
            acc += df * df;
        }
    }
    #pragma unroll
    for (int offx = 32; offx > 0; offx >>= 1)
        acc += __shfl_down(acc, offx, 64);
    __shared__ float ws[4];
    if ((threadIdx.x & 63) == 0) ws[threadIdx.x >> 6] = acc;
    __syncthreads();
    if (threadIdx.x == 0)
        atomicAdd(out, (ws[0] + ws[1] + ws[2] + ws[3]) * inv_E);
}

extern "C" void kernel_launch(void* const* d_in, const int* in_sizes, int n_in,
                              void* d_out, int out_size, void* d_ws, size_t ws_size,
                              hipStream_t stream) {
    const float2* pts      = (const float2*)d_in[0];  // [B,N,2] fp32
    const int*    skel     = (const int*)d_in[1];     // [E,2] int32
    const float*  init_len = (const float*)d_in[2];   // [E]
    float*        out      = (float*)d_out;

    const int B = 64;
    const int E = in_sizes[2];
    const int N = in_sizes[0] / (B * 2);
    const float inv_E = 1.0f / (float)E;

    (void)hipMemsetAsync(out, 0, sizeof(float), stream);

    // tp: 8 slots x N rows x 32 B (f16 x 8 batches)
    const size_t tp_bytes = (size_t)N * 256;
    const bool ok = (ws_size >= tp_bytes) &&
                    ((size_t)in_sizes[0] == (size_t)B * N * 2);

    if (!ok) {
        dim3 grid(((E + 255) / 256) * 8);
        skeleton_loss_fallback<<<grid, 256, 0, stream>>>(
            pts, skel, init_len, out, N, E, inv_E);
        return;
    }

    uint4* tp = (uint4*)d_ws;
    const int nchunk = (N + 1023) / 1024;
    transpose_kernel<<<dim3(8 * nchunk), 1024, 0, stream>>>(pts, tp, N);
    gather_kernel<<<dim3(512), 512, 0, stream>>>(
        tp, (const long long*)skel, init_len, out, N, E, inv_E);
}